// Round 7
// baseline (11.982 us; speedup 1.0000x reference)
//
#include <hip/hip_runtime.h>

#define NPATCH 196
#define IMGS 4   // images per wave

// Closed-form quanvolution (Heisenberg picture; wire w <-> bit 3-w):
//   alpha = a0+rl0
//   f1 = cos(a1+rl1)
//   f0 = cos(rl4)cos(alpha) - sin(rl4)sin(alpha)sin(a2)
//   f2 = cos(rl2)cos(alpha)cos(a2) - sin(rl2)sin(a2)
//   f3 = f1 * cos(a3+rl3) * f2
//   attn raw = cos(f0)  (CX chain leaves Z0 invariant; product state -> <Z0>=cos)
// FOUR images per wave: W float4 loads amortized 4x; x loads for all images
// issued up-front (memory-level parallelism). Zero barriers, zero LDS.

__device__ __forceinline__ float dot4(float4 a, float4 b) {
    return a.x * b.x + a.y * b.y + a.z * b.z + a.w * b.w;
}

// wave64 sum on the VALU pipe via DPP; total lands in lane 63, broadcast via readlane.
__device__ __forceinline__ float wave_sum_bcast(float x) {
#define DPP_STEP(ctrl, rmask)                                                   \
    x += __int_as_float(__builtin_amdgcn_update_dpp(                            \
        0, __float_as_int(x), (ctrl), (rmask), 0xf, true));
    DPP_STEP(0x111, 0xf)   // row_shr:1
    DPP_STEP(0x112, 0xf)   // row_shr:2
    DPP_STEP(0x114, 0xf)   // row_shr:4
    DPP_STEP(0x118, 0xf)   // row_shr:8  -> lane15 of each 16-row = row sum
    DPP_STEP(0x142, 0xa)   // row_bcast:15 into rows 1,3
    DPP_STEP(0x143, 0xc)   // row_bcast:31 into rows 2,3 -> lane63 = total
#undef DPP_STEP
    return __int_as_float(__builtin_amdgcn_readlane(__float_as_int(x), 63));
}

__global__ __launch_bounds__(256, 1) void quanv_fused(
    const float* __restrict__ x, const float* __restrict__ rl,
    const float* __restrict__ W, const float* __restrict__ bias,
    float* __restrict__ out)
{
    const int lane = threadIdx.x & 63;
    const int wave = threadIdx.x >> 6;                 // 4 independent waves
    const int img0 = blockIdx.x * (4 * IMGS) + wave * IMGS;

    // uniform rl trig
    float srl2, crl2, srl4, crl4;
    __sincosf(rl[2], &srl2, &crl2);
    __sincosf(rl[4], &srl4, &crl4);
    const float rl0 = rl[0], rl1 = rl[1], rl3v = rl[3];

    // 98 pairs: all lanes take pair `lane`; lanes 0..33 also take pair lane+64
    const bool has2 = (lane < 34);
    const int q2 = has2 ? (lane + 64) : lane;          // clamped duplicate (weight 0)

    // pair q = patches (2q, 2q+1): 2x4 pixel block = two contiguous float4s
    auto pairf = [&](const float* __restrict__ xb, int q,
                     float4& fA, float4& fB, float& eA, float& eB) {
        const int r = (2 * q) / 14;
        const int c = (2 * q) - r * 14;
        const float4 top = *reinterpret_cast<const float4*>(xb + 56 * r + 2 * c);
        const float4 bot = *reinterpret_cast<const float4*>(xb + 56 * r + 2 * c + 28);
        {
            float sa, ca; __sincosf(top.x + rl0, &sa, &ca);
            float s2, c2; __sincosf(bot.x, &s2, &c2);
            const float f1 = __cosf(top.y + rl1);
            const float cd = __cosf(bot.y + rl3v);
            const float f0 = crl4 * ca - srl4 * sa * s2;
            const float f2 = crl2 * ca * c2 - srl2 * s2;
            fA = make_float4(f0, f1, f2, f1 * cd * f2);
            eA = __expf(__cosf(f0));
        }
        {
            float sa, ca; __sincosf(top.z + rl0, &sa, &ca);
            float s2, c2; __sincosf(bot.z, &s2, &c2);
            const float f1 = __cosf(top.w + rl1);
            const float cd = __cosf(bot.w + rl3v);
            const float f0 = crl4 * ca - srl4 * sa * s2;
            const float f2 = crl2 * ca * c2 - srl2 * s2;
            fB = make_float4(f0, f1, f2, f1 * cd * f2);
            eB = __expf(__cosf(f0));
        }
    };

    // ---- per-image features (loads for all images issue early; full unroll) ----
    float4 g[IMGS][4];        // scaled feature vectors: [img][{A0,B0,A1,B1}]
    float  ev[IMGS][4];
    #pragma unroll
    for (int im = 0; im < IMGS; ++im) {
        const float* __restrict__ xb = x + (size_t)(img0 + im) * 784;
        pairf(xb, lane, g[im][0], g[im][1], ev[im][0], ev[im][1]);
        pairf(xb, q2,   g[im][2], g[im][3], ev[im][2], ev[im][3]);
        if (!has2) { ev[im][2] = 0.f; ev[im][3] = 0.f; }
    }

    // ---- softmax denominators: IMGS independent DPP chains ----
    #pragma unroll
    for (int im = 0; im < IMGS; ++im) {
        const float inv = 1.0f /
            wave_sum_bcast(ev[im][0] + ev[im][1] + ev[im][2] + ev[im][3]);
        #pragma unroll
        for (int j = 0; j < 4; ++j) {
            const float w = ev[im][j] * inv;
            g[im][j] = make_float4(g[im][j].x * w, g[im][j].y * w,
                                   g[im][j].z * w, g[im][j].w * w);
        }
    }

    // ---- partial logits: W float4s loaded ONCE, used for all IMGS images ----
    const float4* __restrict__ W4 = reinterpret_cast<const float4*>(W);
    float acc[IMGS][10];
    #pragma unroll
    for (int k = 0; k < 10; ++k) {
        const int kb = k * NPATCH;
        const float4 w0 = W4[kb + 2 * lane];
        const float4 w1 = W4[kb + 2 * lane + 1];
        const float4 w2 = W4[kb + 2 * q2];
        const float4 w3 = W4[kb + 2 * q2 + 1];
        #pragma unroll
        for (int im = 0; im < IMGS; ++im) {
            acc[im][k] = dot4(g[im][0], w0) + dot4(g[im][1], w1)
                       + dot4(g[im][2], w2) + dot4(g[im][3], w3);
        }
    }

    // ---- 10*IMGS wave reductions -> uniform logits ----
    float lg[IMGS][10];
    #pragma unroll
    for (int k = 0; k < 10; ++k) {
        const float bk = bias[k];
        #pragma unroll
        for (int im = 0; im < IMGS; ++im)
            lg[im][k] = wave_sum_bcast(acc[im][k]) + bk;
    }

    // ---- log_softmax over 10 (uniform per-lane), all images ----
    #pragma unroll
    for (int im = 0; im < IMGS; ++im) {
        float m2 = lg[im][0];
        #pragma unroll
        for (int k = 1; k < 10; ++k) m2 = fmaxf(m2, lg[im][k]);
        float ssum = 0.f;
        #pragma unroll
        for (int k = 0; k < 10; ++k) ssum += __expf(lg[im][k] - m2);
        const float lse = m2 + __logf(ssum);
        if (lane < 10) {
            float myv = lg[im][0];
            #pragma unroll
            for (int k = 1; k < 10; ++k) myv = (lane == k) ? lg[im][k] : myv;
            out[(size_t)(img0 + im) * 10 + lane] = myv - lse;
        }
    }
}

extern "C" void kernel_launch(void* const* d_in, const int* in_sizes, int n_in,
                              void* d_out, int out_size, void* d_ws, size_t ws_size,
                              hipStream_t stream) {
    const float* x    = (const float*)d_in[0];
    const float* rl   = (const float*)d_in[1];
    const float* W    = (const float*)d_in[2];
    const float* bias = (const float*)d_in[3];
    float* out = (float*)d_out;
    const int B = in_sizes[0] / 784;              // 4096
    quanv_fused<<<B / (4 * IMGS), 256, 0, stream>>>(x, rl, W, bias, out);
}

// Round 8
// 11.015 us; speedup vs baseline: 1.0878x; 1.0878x over previous
//
#include <hip/hip_runtime.h>

#define NPATCH 196

// Closed-form quanvolution (Heisenberg picture; wire w <-> bit 3-w):
//   alpha = a0+rl0
//   f1 = cos(a1+rl1)
//   f0 = cos(rl4)cos(alpha) - sin(rl4)sin(alpha)sin(a2)
//   f2 = cos(rl2)cos(alpha)cos(a2) - sin(rl2)sin(a2)
//   f3 = f1 * cos(a3+rl3) * f2
//   attn raw = cos(f0)  (CX chain leaves Z0 invariant; product state -> <Z0>=cos)
// TWO images per wave (best measured config): W float4 loads shared by both
// images' dot products. Zero barriers, zero LDS.
// Measured ladder: 26.0 (sim) -> 20.2 (closed form) -> 13.4 (wave/image)
//   -> 13.1 (DPP) -> 12.2 (no-LDS pairs) -> 11.57 (2 img/wave, THIS)
//   -> 11.98 (4 img/wave, regressed — reverted).
// Residual ~10 us is the fixed launch/replay floor; kernel GPU time ~1.5 us.

__device__ __forceinline__ float dot4(float4 a, float4 b) {
    return a.x * b.x + a.y * b.y + a.z * b.z + a.w * b.w;
}

// wave64 sum on the VALU pipe via DPP; total lands in lane 63, broadcast via readlane.
__device__ __forceinline__ float wave_sum_bcast(float x) {
#define DPP_STEP(ctrl, rmask)                                                   \
    x += __int_as_float(__builtin_amdgcn_update_dpp(                            \
        0, __float_as_int(x), (ctrl), (rmask), 0xf, true));
    DPP_STEP(0x111, 0xf)   // row_shr:1
    DPP_STEP(0x112, 0xf)   // row_shr:2
    DPP_STEP(0x114, 0xf)   // row_shr:4
    DPP_STEP(0x118, 0xf)   // row_shr:8  -> lane15 of each 16-row = row sum
    DPP_STEP(0x142, 0xa)   // row_bcast:15 into rows 1,3
    DPP_STEP(0x143, 0xc)   // row_bcast:31 into rows 2,3 -> lane63 = total
#undef DPP_STEP
    return __int_as_float(__builtin_amdgcn_readlane(__float_as_int(x), 63));
}

__global__ __launch_bounds__(256) void quanv_fused(
    const float* __restrict__ x, const float* __restrict__ rl,
    const float* __restrict__ W, const float* __restrict__ bias,
    float* __restrict__ out)
{
    const int lane = threadIdx.x & 63;
    const int wave = threadIdx.x >> 6;              // 4 independent waves
    const int imgA = blockIdx.x * 8 + 2 * wave;     // wave owns images imgA, imgA+1
    const int imgB = imgA + 1;

    const float* __restrict__ xa = x + (size_t)imgA * 784;
    const float* __restrict__ xbp = x + (size_t)imgB * 784;

    // uniform rl trig
    float srl2, crl2, srl4, crl4;
    __sincosf(rl[2], &srl2, &crl2);
    __sincosf(rl[4], &srl4, &crl4);
    const float rl0 = rl[0], rl1 = rl[1], rl3v = rl[3];

    // per-pair closed form: pair q = patches (2q, 2q+1), pixels = 2 contiguous float4
    auto pairf = [&](const float* __restrict__ xb, int q,
                     float4& fA, float4& fB, float& eA, float& eB) {
        const int r = (2 * q) / 14;
        const int c = (2 * q) - r * 14;
        const float4 top = *reinterpret_cast<const float4*>(xb + 56 * r + 2 * c);
        const float4 bot = *reinterpret_cast<const float4*>(xb + 56 * r + 2 * c + 28);
        {
            float sa, ca; __sincosf(top.x + rl0, &sa, &ca);
            float s2, c2; __sincosf(bot.x, &s2, &c2);
            const float f1 = __cosf(top.y + rl1);
            const float cd = __cosf(bot.y + rl3v);
            const float f0 = crl4 * ca - srl4 * sa * s2;
            const float f2 = crl2 * ca * c2 - srl2 * s2;
            fA = make_float4(f0, f1, f2, f1 * cd * f2);
            eA = __expf(__cosf(f0));
        }
        {
            float sa, ca; __sincosf(top.z + rl0, &sa, &ca);
            float s2, c2; __sincosf(bot.z, &s2, &c2);
            const float f1 = __cosf(top.w + rl1);
            const float cd = __cosf(bot.w + rl3v);
            const float f0 = crl4 * ca - srl4 * sa * s2;
            const float f2 = crl2 * ca * c2 - srl2 * s2;
            fB = make_float4(f0, f1, f2, f1 * cd * f2);
            eB = __expf(__cosf(f0));
        }
    };

    // 98 pairs: all lanes take pair `lane`; lanes 0..33 also take pair lane+64
    const bool has2 = (lane < 34);
    const int q2 = has2 ? (lane + 64) : lane;       // clamped duplicate (weight 0)

    // image A
    float4 aA0, aB0, aA1, aB1; float eaA0, eaB0, eaA1, eaB1;
    pairf(xa, lane, aA0, aB0, eaA0, eaB0);
    pairf(xa, q2,   aA1, aB1, eaA1, eaB1);
    if (!has2) { eaA1 = 0.f; eaB1 = 0.f; }
    // image B
    float4 bA0, bB0, bA1, bB1; float ebA0, ebB0, ebA1, ebB1;
    pairf(xbp, lane, bA0, bB0, ebA0, ebB0);
    pairf(xbp, q2,   bA1, bB1, ebA1, ebB1);
    if (!has2) { ebA1 = 0.f; ebB1 = 0.f; }

    // softmax denominators (raw = cos(f0) in [-1,1] -> no max pass)
    const float invA = 1.0f / wave_sum_bcast(eaA0 + eaB0 + eaA1 + eaB1);
    const float invB = 1.0f / wave_sum_bcast(ebA0 + ebB0 + ebA1 + ebB1);

    auto scale4 = [](float4 f, float w) {
        return make_float4(f.x * w, f.y * w, f.z * w, f.w * w);
    };
    const float4 gA0 = scale4(aA0, eaA0 * invA), gB0 = scale4(aB0, eaB0 * invA);
    const float4 gA1 = scale4(aA1, eaA1 * invA), gB1 = scale4(aB1, eaB1 * invA);
    const float4 hA0 = scale4(bA0, ebA0 * invB), hB0 = scale4(bB0, ebB0 * invB);
    const float4 hA1 = scale4(bA1, ebA1 * invB), hB1 = scale4(bB1, ebB1 * invB);

    // partial logits: W float4s loaded ONCE, used for both images
    const float4* __restrict__ W4 = reinterpret_cast<const float4*>(W);
    float accA[10], accB[10];
    #pragma unroll
    for (int k = 0; k < 10; ++k) {
        const int kb = k * NPATCH;
        const float4 w0 = W4[kb + 2 * lane];
        const float4 w1 = W4[kb + 2 * lane + 1];
        const float4 w2 = W4[kb + 2 * q2];
        const float4 w3 = W4[kb + 2 * q2 + 1];
        accA[k] = dot4(gA0, w0) + dot4(gB0, w1) + dot4(gA1, w2) + dot4(gB1, w3);
        accB[k] = dot4(hA0, w0) + dot4(hB0, w1) + dot4(hA1, w2) + dot4(hB1, w3);
    }

    // 20 wave reductions -> uniform logits for both images
    float lgA[10], lgB[10];
    #pragma unroll
    for (int k = 0; k < 10; ++k) {
        const float bk = bias[k];
        lgA[k] = wave_sum_bcast(accA[k]) + bk;
        lgB[k] = wave_sum_bcast(accB[k]) + bk;
    }

    // log_softmax over 10 (uniform per-lane), both images
    float mA = lgA[0], mB = lgB[0];
    #pragma unroll
    for (int k = 1; k < 10; ++k) { mA = fmaxf(mA, lgA[k]); mB = fmaxf(mB, lgB[k]); }
    float sA = 0.f, sB = 0.f;
    #pragma unroll
    for (int k = 0; k < 10; ++k) { sA += __expf(lgA[k] - mA); sB += __expf(lgB[k] - mB); }
    const float lseA = mA + __logf(sA);
    const float lseB = mB + __logf(sB);

    if (lane < 10) {
        float vA = lgA[0], vB = lgB[0];
        #pragma unroll
        for (int k = 1; k < 10; ++k) {
            vA = (lane == k) ? lgA[k] : vA;
            vB = (lane == k) ? lgB[k] : vB;
        }
        out[(size_t)imgA * 10 + lane] = vA - lseA;
        out[(size_t)imgB * 10 + lane] = vB - lseB;
    }
}

extern "C" void kernel_launch(void* const* d_in, const int* in_sizes, int n_in,
                              void* d_out, int out_size, void* d_ws, size_t ws_size,
                              hipStream_t stream) {
    const float* x    = (const float*)d_in[0];
    const float* rl   = (const float*)d_in[1];
    const float* W    = (const float*)d_in[2];
    const float* bias = (const float*)d_in[3];
    float* out = (float*)d_out;
    const int B = in_sizes[0] / 784;          // 4096
    quanv_fused<<<B / 8, 256, 0, stream>>>(x, rl, W, bias, out);
}